// Round 8
// baseline (645.774 us; speedup 1.0000x reference)
//
#include <hip/hip_runtime.h>
#include <hip/hip_fp16.h>

#define IN_DIM 128
#define NCLS 40
#define AS_STRIDE 136   // halves; 272 B row stride, 16 B aligned

// ---------------- degree / norm ----------------

__global__ __launch_bounds__(256) void deg_kernel(const int* __restrict__ src, const int* __restrict__ dst,
                                                  int* __restrict__ ds, int* __restrict__ dd, int E) {
    int e = blockIdx.x * 256 + threadIdx.x;
    if (e < E) {
        atomicAdd(&ds[src[e]], 1);
        atomicAdd(&dd[dst[e]], 1);
    }
}

__global__ __launch_bounds__(256) void norm_kernel(const int* __restrict__ ds, const int* __restrict__ dd,
                                                   float* __restrict__ ns, float* __restrict__ nd, int N) {
    int i = blockIdx.x * 256 + threadIdx.x;
    if (i < N) {
        ns[i] = ds[i] > 0 ? rsqrtf((float)ds[i]) : 0.f;
        nd[i] = dd[i] > 0 ? rsqrtf((float)dd[i]) : 0.f;
    }
}

// ---------------- exclusive scan of in-degrees -> row_ptr ----------------

__global__ __launch_bounds__(256) void scan_partial(const int* __restrict__ dd, int* __restrict__ bsums, int N) {
    __shared__ int sd[256];
    int t = threadIdx.x;
    int base = blockIdx.x * 1024 + t * 4;
    int s = 0;
#pragma unroll
    for (int k = 0; k < 4; ++k) { int i = base + k; if (i < N) s += dd[i]; }
    sd[t] = s;
    __syncthreads();
    for (int off = 128; off > 0; off >>= 1) {
        if (t < off) sd[t] += sd[t + off];
        __syncthreads();
    }
    if (t == 0) bsums[blockIdx.x] = sd[0];
}

__global__ void scan_bsums(int* __restrict__ bsums, int nb) {
    int lane = threadIdx.x;
    int carry = 0;
    for (int c = 0; c < nb; c += 64) {
        int i = c + lane;
        int orig = (i < nb) ? bsums[i] : 0;
        int v = orig;
#pragma unroll
        for (int off = 1; off < 64; off <<= 1) {
            int u = __shfl_up(v, off);
            if (lane >= off) v += u;
        }
        if (i < nb) bsums[i] = carry + v - orig;   // exclusive
        carry += __shfl(v, 63);
    }
}

__global__ __launch_bounds__(256) void scan_final(const int* __restrict__ dd, const int* __restrict__ bsums,
                                                  int* __restrict__ cursor, int N) {
    __shared__ int sd[256];
    int t = threadIdx.x;
    int base = blockIdx.x * 1024 + t * 4;
    int v[4]; int s = 0;
#pragma unroll
    for (int k = 0; k < 4; ++k) { int i = base + k; v[k] = (i < N) ? dd[i] : 0; s += v[k]; }
    sd[t] = s;
    __syncthreads();
    for (int off = 1; off < 256; off <<= 1) {
        int u = (t >= off) ? sd[t - off] : 0;
        __syncthreads();
        sd[t] += u;
        __syncthreads();
    }
    int excl = sd[t] - s + bsums[blockIdx.x];
#pragma unroll
    for (int k = 0; k < 4; ++k) {
        int i = base + k;
        if (i < N) cursor[i] = excl;
        excl += v[k];
    }
}

__global__ __launch_bounds__(256) void fill_csr(const int* __restrict__ src, const int* __restrict__ dst,
                                                int* __restrict__ cursor, int* __restrict__ csr, int E) {
    int e = blockIdx.x * 256 + threadIdx.x;
    if (e < E) {
        int slot = atomicAdd(&cursor[dst[e]], 1);
        csr[slot] = src[e];
    }
}

// ---------------- helpers ----------------

__device__ __forceinline__ float4 zero4() { return make_float4(0.f, 0.f, 0.f, 0.f); }

__device__ __forceinline__ void fma4(float4& acc, float s, const float4& wv) {
    acc.x = fmaf(s, wv.x, acc.x);
    acc.y = fmaf(s, wv.y, acc.y);
    acc.z = fmaf(s, wv.z, acc.z);
    acc.w = fmaf(s, wv.w, acc.w);
}

__device__ __forceinline__ float4 shfl_xor4(const float4& v, int m) {
    float4 r;
    r.x = __shfl_xor(v.x, m);
    r.y = __shfl_xor(v.y, m);
    r.z = __shfl_xor(v.z, m);
    r.w = __shfl_xor(v.w, m);
    return r;
}

__device__ __forceinline__ void addr4(float4& a, const float4& b) {
    a.x += b.x; a.y += b.y; a.z += b.z; a.w += b.w;
}

// accumulate 8 halves (one int4) scaled by m into two float4s
__device__ __forceinline__ void acc_h8(float4& a0, float4& a1, const int4& v, float m) {
    const __half2* h = (const __half2*)&v;
    float2 f0 = __half22float2(h[0]);
    float2 f1 = __half22float2(h[1]);
    float2 f2 = __half22float2(h[2]);
    float2 f3 = __half22float2(h[3]);
    a0.x = fmaf(f0.x, m, a0.x); a0.y = fmaf(f0.y, m, a0.y);
    a0.z = fmaf(f1.x, m, a0.z); a0.w = fmaf(f1.y, m, a0.w);
    a1.x = fmaf(f2.x, m, a1.x); a1.y = fmaf(f2.y, m, a1.y);
    a1.z = fmaf(f3.x, m, a1.z); a1.w = fmaf(f3.y, m, a1.w);
}

__device__ __forceinline__ int4 pack_h8(const float4& o0, const float4& o1) {
    int4 p;
    __half2* ph = (__half2*)&p;
    ph[0] = __float22half2_rn(make_float2(o0.x, o0.y));
    ph[1] = __float22half2_rn(make_float2(o0.z, o0.w));
    ph[2] = __float22half2_rn(make_float2(o1.x, o1.y));
    ph[3] = __float22half2_rn(make_float2(o1.z, o1.w));
    return p;
}

// ---------------- prescale: xh[i] = fp16(x[i] * ns[row]) ----------------

__global__ __launch_bounds__(256) void prescale_kernel(const float* __restrict__ x, const float* __restrict__ ns,
                                                       __half* __restrict__ xh, int N) {
    int tid = blockIdx.x * 256 + threadIdx.x;     // one per 8 floats
    if (tid >= N * 16) return;
    int row = tid >> 4;
    int c = tid & 15;
    float s = ns[row];
    const float4* xp = (const float4*)x + (size_t)row * 32 + c * 2;
    float4 v0 = xp[0], v1 = xp[1];
    v0.x *= s; v0.y *= s; v0.z *= s; v0.w *= s;
    v1.x *= s; v1.y *= s; v1.z *= s; v1.w *= s;
    ((int4*)xh)[tid] = pack_h8(v0, v1);
}

// ---------------- fused gather(fp16) + GEMM layer ----------------
// block = 64 dst rows, 256 threads. Gather: 4 waves x 16 rows, 2 rows
// interleaved; 4 edge-slots (g=lane>>4) x 16 chunks (c=lane&15, int4 = 8
// halves). fp32 accumulate, 2-round shfl_xor reduce, nd-scale, pack fp16
// to LDS (17.4 KB -> ~6 blocks/CU with launch_bounds(256,6)). GEMM: thread
// = 4 rows x 8 cols, A from LDS fp16, W from L2 fp32, epilogue
// bias+relu(+ns) -> fp16.

template<int SCALE_NS>
__global__ __launch_bounds__(256, 6) void fused_layer(const __half* __restrict__ xh, const int* __restrict__ csr,
                                                      const int* __restrict__ cursor, const float* __restrict__ ns,
                                                      const float* __restrict__ nd, const float* __restrict__ W,
                                                      const float* __restrict__ bias, __half* __restrict__ out, int N) {
    __shared__ __half As[64 * AS_STRIDE];
    int t = threadIdx.x;
    int lane = t & 63;
    int wv = t >> 6;
    int row0 = blockIdx.x * 64;
    int g = lane >> 4;     // edge slot 0..3
    int c = lane & 15;     // chunk: halves [c*8, c*8+8)
    const int4* xi = (const int4*)xh;

    // ---- gather phase: 8 row-pairs per wave ----
    for (int rr = 0; rr < 16; rr += 2) {
        int rA = row0 + wv * 16 + rr;
        int rB = rA + 1;
        int sA = 0, eA = 0, sB = 0, eB = 0;
        if (rA < N) { sA = rA ? cursor[rA - 1] : 0; eA = cursor[rA]; }
        if (rB < N) { sB = cursor[rB - 1]; eB = cursor[rB]; }
        float4 aA0 = zero4(), aA1 = zero4(), aB0 = zero4(), aB1 = zero4();
        int oA = sA, oB = sB;
        while (oA < eA || oB < eB) {
            int ea0 = oA + g, ea1 = oA + 4 + g;
            int eb0 = oB + g, eb1 = oB + 4 + g;
            float ma0 = (ea0 < eA) ? 1.f : 0.f;
            float ma1 = (ea1 < eA) ? 1.f : 0.f;
            float mb0 = (eb0 < eB) ? 1.f : 0.f;
            float mb1 = (eb1 < eB) ? 1.f : 0.f;
            int ia0 = (ea0 < eA) ? csr[ea0] : 0;
            int ia1 = (ea1 < eA) ? csr[ea1] : 0;
            int ib0 = (eb0 < eB) ? csr[eb0] : 0;
            int ib1 = (eb1 < eB) ? csr[eb1] : 0;
            int4 va0 = xi[(size_t)ia0 * 16 + c];
            int4 va1 = xi[(size_t)ia1 * 16 + c];
            int4 vb0 = xi[(size_t)ib0 * 16 + c];
            int4 vb1 = xi[(size_t)ib1 * 16 + c];
            acc_h8(aA0, aA1, va0, ma0);
            acc_h8(aA0, aA1, va1, ma1);
            acc_h8(aB0, aB1, vb0, mb0);
            acc_h8(aB0, aB1, vb1, mb1);
            oA += 8; oB += 8;
        }
        // reduce across the 4 edge slots (lane bits 4, 5)
#pragma unroll
        for (int m = 16; m <= 32; m <<= 1) {
            addr4(aA0, shfl_xor4(aA0, m));
            addr4(aA1, shfl_xor4(aA1, m));
            addr4(aB0, shfl_xor4(aB0, m));
            addr4(aB1, shfl_xor4(aB1, m));
        }
        if (g == 0) {
            if (rA < N) {
                float sc = nd[rA];
                aA0.x *= sc; aA0.y *= sc; aA0.z *= sc; aA0.w *= sc;
                aA1.x *= sc; aA1.y *= sc; aA1.z *= sc; aA1.w *= sc;
                *(int4*)&As[(wv * 16 + rr) * AS_STRIDE + c * 8] = pack_h8(aA0, aA1);
            }
            if (rB < N) {
                float sc = nd[rB];
                aB0.x *= sc; aB0.y *= sc; aB0.z *= sc; aB0.w *= sc;
                aB1.x *= sc; aB1.y *= sc; aB1.z *= sc; aB1.w *= sc;
                *(int4*)&As[(wv * 16 + rr + 1) * AS_STRIDE + c * 8] = pack_h8(aB0, aB1);
            }
        }
    }
    __syncthreads();

    // ---- GEMM phase: thread = 4 rows x 8 cols ----
    int rg = t >> 4;
    int cgp = t & 15;
    int rbase = rg * 4;
    const float4* Wg = (const float4*)W;
    float4 acc[4][2];
#pragma unroll
    for (int m = 0; m < 4; ++m) { acc[m][0] = zero4(); acc[m][1] = zero4(); }
#pragma unroll 2
    for (int k4 = 0; k4 < 32; ++k4) {
        int k0 = k4 * 4;
        float4 a[4];
#pragma unroll
        for (int m = 0; m < 4; ++m) {
            uint2 raw = *(const uint2*)&As[(rbase + m) * AS_STRIDE + k0];
            const __half2* hp = (const __half2*)&raw;
            float2 f0 = __half22float2(hp[0]);
            float2 f1 = __half22float2(hp[1]);
            a[m] = make_float4(f0.x, f0.y, f1.x, f1.y);
        }
        float4 w[4][2];
#pragma unroll
        for (int j = 0; j < 4; ++j) {
            w[j][0] = Wg[(k0 + j) * 32 + cgp * 2 + 0];
            w[j][1] = Wg[(k0 + j) * 32 + cgp * 2 + 1];
        }
#pragma unroll
        for (int m = 0; m < 4; ++m) {
            fma4(acc[m][0], a[m].x, w[0][0]); fma4(acc[m][1], a[m].x, w[0][1]);
            fma4(acc[m][0], a[m].y, w[1][0]); fma4(acc[m][1], a[m].y, w[1][1]);
            fma4(acc[m][0], a[m].z, w[2][0]); fma4(acc[m][1], a[m].z, w[2][1]);
            fma4(acc[m][0], a[m].w, w[3][0]); fma4(acc[m][1], a[m].w, w[3][1]);
        }
    }

    float4 bb0 = ((const float4*)bias)[cgp * 2 + 0];
    float4 bb1 = ((const float4*)bias)[cgp * 2 + 1];
#pragma unroll
    for (int m = 0; m < 4; ++m) {
        int gr = row0 + rbase + m;
        if (gr < N) {
            float4 o0, o1;
            o0.x = fmaxf(acc[m][0].x + bb0.x, 0.f); o0.y = fmaxf(acc[m][0].y + bb0.y, 0.f);
            o0.z = fmaxf(acc[m][0].z + bb0.z, 0.f); o0.w = fmaxf(acc[m][0].w + bb0.w, 0.f);
            o1.x = fmaxf(acc[m][1].x + bb1.x, 0.f); o1.y = fmaxf(acc[m][1].y + bb1.y, 0.f);
            o1.z = fmaxf(acc[m][1].z + bb1.z, 0.f); o1.w = fmaxf(acc[m][1].w + bb1.w, 0.f);
            if (SCALE_NS) {
                float s = ns[gr];
                o0.x *= s; o0.y *= s; o0.z *= s; o0.w *= s;
                o1.x *= s; o1.y *= s; o1.z *= s; o1.w *= s;
            }
            ((int4*)out)[(size_t)gr * 16 + cgp] = pack_h8(o0, o1);
        }
    }
}

// ---------------- GEMM 128(fp16) -> 40, epilogue *ns -> fp16 y (stride 40 halves) ----------

__global__ __launch_bounds__(256) void gemm40_kernel(const __half* __restrict__ A, const float* __restrict__ W,
                                                     const float* __restrict__ ns, __half* __restrict__ y, int N) {
    __shared__ float Ws[128 * NCLS];   // 20 KB
    __shared__ float As[32 * 132];     // 16.5 KB
    int t = threadIdx.x;
    int row0 = blockIdx.x * 32;

#pragma unroll
    for (int i = 0; i < 5; ++i) {
        int idx = t + 256 * i;
        ((float4*)Ws)[idx] = ((const float4*)W)[idx];
    }
    // stage A (fp16 -> fp32): 32 rows x 16 int4
#pragma unroll
    for (int i = 0; i < 2; ++i) {
        int idx = t + 256 * i;        // 0..511
        int r = idx >> 4;
        int c16 = idx & 15;
        int gr = row0 + r;
        int4 v = make_int4(0, 0, 0, 0);
        if (gr < N) v = ((const int4*)A)[(size_t)gr * 16 + c16];
        const __half2* h = (const __half2*)&v;
        float2 f0 = __half22float2(h[0]);
        float2 f1 = __half22float2(h[1]);
        float2 f2 = __half22float2(h[2]);
        float2 f3 = __half22float2(h[3]);
        float* dp = &As[r * 132 + c16 * 8];
        dp[0] = f0.x; dp[1] = f0.y; dp[2] = f1.x; dp[3] = f1.y;
        dp[4] = f2.x; dp[5] = f2.y; dp[6] = f3.x; dp[7] = f3.y;
    }
    __syncthreads();

    int row = t >> 3;
    int cg = t & 7;
    float acc[5] = {0.f, 0.f, 0.f, 0.f, 0.f};
#pragma unroll 2
    for (int k4 = 0; k4 < 32; ++k4) {
        float4 a = *(const float4*)&As[row * 132 + k4 * 4];
#pragma unroll
        for (int j = 0; j < 4; ++j) {
            float av = (j == 0) ? a.x : (j == 1) ? a.y : (j == 2) ? a.z : a.w;
            const float* wp = &Ws[(k4 * 4 + j) * NCLS + cg * 5];
            acc[0] = fmaf(av, wp[0], acc[0]);
            acc[1] = fmaf(av, wp[1], acc[1]);
            acc[2] = fmaf(av, wp[2], acc[2]);
            acc[3] = fmaf(av, wp[3], acc[3]);
            acc[4] = fmaf(av, wp[4], acc[4]);
        }
    }
    int gr = row0 + row;
    if (gr < N) {
        float s = ns[gr];
        __half* yp = y + (size_t)gr * NCLS + cg * 5;
        yp[0] = __float2half_rn(acc[0] * s);
        yp[1] = __float2half_rn(acc[1] * s);
        yp[2] = __float2half_rn(acc[2] * s);
        yp[3] = __float2half_rn(acc[3] * s);
        yp[4] = __float2half_rn(acc[4] * s);
    }
}

// ---------------- gather 40-d (fp16 y, pre-scaled by ns) + *nd + b2 -> out (fp32) ----------

__global__ __launch_bounds__(256) void gather40_finish(const __half* __restrict__ y, const int* __restrict__ csr,
                                                       const int* __restrict__ cursor, const float* __restrict__ nd,
                                                       const float* __restrict__ b2, float* __restrict__ out, int N) {
    int t = threadIdx.x;
    int lane = t & 63;
    int r = blockIdx.x * 4 + (t >> 6);
    if (r >= N) return;
    int g = lane >> 3;
    int c = lane & 7;
    int start = r ? cursor[r - 1] : 0;
    int end = cursor[r];
    float4 a0 = zero4(), a1 = zero4();
    const int4* yi = (const int4*)y;
    for (int base = start; base < end; base += 16) {
        int e0 = base + g, e1 = base + 8 + g;
        float m0 = (e0 < end) ? 1.f : 0.f;
        float m1 = (e1 < end) ? 1.f : 0.f;
        int i0 = (e0 < end) ? csr[e0] : 0;
        int i1 = (e1 < end) ? csr[e1] : 0;
        if (c < 5) {
            int4 v0 = yi[(size_t)i0 * 5 + c];
            int4 v1 = yi[(size_t)i1 * 5 + c];
            acc_h8(a0, a1, v0, m0);
            acc_h8(a0, a1, v1, m1);
        }
    }
#pragma unroll
    for (int m = 8; m <= 32; m <<= 1) {
        addr4(a0, shfl_xor4(a0, m));
        addr4(a1, shfl_xor4(a1, m));
    }
    if (g == 0 && c < 5) {
        float s = nd[r];
        float4 b20 = ((const float4*)b2)[c * 2 + 0];
        float4 b21 = ((const float4*)b2)[c * 2 + 1];
        float4 o0, o1;
        o0.x = fmaf(a0.x, s, b20.x); o0.y = fmaf(a0.y, s, b20.y);
        o0.z = fmaf(a0.z, s, b20.z); o0.w = fmaf(a0.w, s, b20.w);
        o1.x = fmaf(a1.x, s, b21.x); o1.y = fmaf(a1.y, s, b21.y);
        o1.z = fmaf(a1.z, s, b21.z); o1.w = fmaf(a1.w, s, b21.w);
        float* op = out + (size_t)r * NCLS + c * 8;
        *(float4*)(op + 0) = o0;
        *(float4*)(op + 4) = o1;
    }
}

extern "C" void kernel_launch(void* const* d_in, const int* in_sizes, int n_in,
                              void* d_out, int out_size, void* d_ws, size_t ws_size,
                              hipStream_t stream) {
    const float* x  = (const float*)d_in[0];
    const int* src  = (const int*)d_in[1];
    const int* dst  = (const int*)d_in[2];
    const float* W0 = (const float*)d_in[3];
    const float* b0 = (const float*)d_in[4];
    const float* W1 = (const float*)d_in[5];
    const float* b1 = (const float*)d_in[6];
    const float* W2 = (const float*)d_in[7];
    const float* b2 = (const float*)d_in[8];
    float* out = (float*)d_out;

    int N = in_sizes[0] / IN_DIM;
    int E = in_sizes[1];

    float* base = (float*)d_ws;
    float* ns   = base;                       // N
    float* ndn  = base + (size_t)N;           // N
    int* dsg    = (int*)(base + 2 * (size_t)N);
    int* ddg    = (int*)(base + 3 * (size_t)N);
    int* cursor = (int*)(base + 4 * (size_t)N);
    int* bsums  = (int*)(base + 5 * (size_t)N);          // 1024
    int* csr    = (int*)(base + 5 * (size_t)N + 1024);   // E
    __half* xh  = (__half*)(csr + (size_t)E);            // N x 128 halves
    __half* h0  = xh + (size_t)N * 128;                  // N x 128 halves
    __half* h1  = h0 + (size_t)N * 128;                  // N x 128 halves
    __half* yh  = h1 + (size_t)N * 128;                  // N x 40 halves

    int nb = (N + 1023) / 1024;

    (void)hipMemsetAsync(dsg, 0, 2 * (size_t)N * sizeof(int), stream);
    deg_kernel<<<(E + 255) / 256, 256, 0, stream>>>(src, dst, dsg, ddg, E);
    norm_kernel<<<(N + 255) / 256, 256, 0, stream>>>(dsg, ddg, ns, ndn, N);

    scan_partial<<<nb, 256, 0, stream>>>(ddg, bsums, N);
    scan_bsums<<<1, 64, 0, stream>>>(bsums, nb);
    scan_final<<<nb, 256, 0, stream>>>(ddg, bsums, cursor, N);
    fill_csr<<<(E + 255) / 256, 256, 0, stream>>>(src, dst, cursor, csr, E);

    // xh = fp16(x * ns)
    prescale_kernel<<<(N * 16 + 255) / 256, 256, 0, stream>>>(x, ns, xh, N);

    int gblk64 = (N + 63) / 64;
    int gblk4  = (N + 3) / 4;

    // layer 0: gather(xh) -> *nd -> @W0+b0 -> relu -> *ns -> fp16 h0
    fused_layer<1><<<gblk64, 256, 0, stream>>>(xh, csr, cursor, ns, ndn, W0, b0, h0, N);
    // layer 1: gather(h0) -> *nd -> @W1+b1 -> relu -> fp16 h1
    fused_layer<0><<<gblk64, 256, 0, stream>>>(h0, csr, cursor, ns, ndn, W1, b1, h1, N);
    // layer 2: y = (h1 @ W2) * ns (fp16, stride 40) -> gather40 -> *nd + b2
    gemm40_kernel<<<(N + 31) / 32, 256, 0, stream>>>(h1, W2, ns, yh, N);
    gather40_finish<<<gblk4, 256, 0, stream>>>(yh, csr, cursor, ndn, b2, out, N);
}